// Round 9
// baseline (243.512 us; speedup 1.0000x reference)
//
#include <hip/hip_runtime.h>
#include <hip/hip_bf16.h>

// NNConv collapsed algebraically, 2 dispatches, ZERO global atomics, stateless:
//   K1 k_score : s[e] = sum_c u_e[c]*x[row[e],c],
//                u_e[c] = bsum[c] + sum_d ea[e,d]*Wsum[d,c]
//                (Wsum/bsum built per block in LDS; plain coalesced store s[e])
//   K2 k_reduce_gemm : each block owns a node slice; scans col[] once,
//                gathers s[e] on hit into LDS seg/cnt (explicitly zeroed),
//                mean = seg/(64*cnt), then x@root + bias + mean for the slice.
//
// Session ladder (gfx950, measured):
//   grid.sync ~70us/barrier (R4) ; manual spin+fence ~70us (R6)
//   dispatch boundary ~2-3us (R5) ; global atomic scatter 2/edge ~30-43us (R7)
//   halved+privatized atomics -> 97.9us total (R8, failed numerically)
//   => this round: no grid-wide sync, no global atomics, no cross-call state.
// R8 post-timing failure proved workspace poison is NOT re-applied between
// timed replays: any scheme must be invariant to re-execution. Here every
// workspace byte (s[]) is fully rewritten each call; LDS accumulators are
// zeroed in-kernel.

#define CC 64
#define DE 16
#define PAD 65    // xs row stride: 65%32=1 -> nl groups hit distinct banks
#define NB2 64    // reducer blocks (each owns ceil(N/NB2) nodes)
#define SLMAX 160 // max slice size supported by LDS arrays

// ---- Kernel 1: per-block Wsum/bsum in LDS + per-edge direct matvec -> s[e] -
__global__ __launch_bounds__(256) void k_score(const float* __restrict__ W,
                                               const float* __restrict__ b,
                                               const float* __restrict__ x,
                                               const int* __restrict__ ei,
                                               const float* __restrict__ ea,
                                               float* __restrict__ s,
                                               int E) {
    __shared__ float ws[1024 + CC];   // Wsum(16x64) then bsum(64)
    const int tid = threadIdx.x;

    // Wsum/bsum: 1088 reductions of 64 contiguous floats (W=262KB, L2-resident)
    for (int p = tid; p < 1024 + CC; p += 256) {
        const float4* src = (p < 1024) ? (const float4*)(W + (size_t)p * CC)
                                       : (const float4*)(b + (size_t)(p - 1024) * CC);
        float v = 0.f;
#pragma unroll
        for (int i = 0; i < 16; ++i) { float4 q = src[i]; v += q.x + q.y + q.z + q.w; }
        ws[p] = v;
    }
    __syncthreads();

    int e = blockIdx.x * 256 + tid;
    if (e >= E) return;

    const int r = ei[e];

    const float4* a4 = (const float4*)(ea + (size_t)e * DE);
    float4 av[4];
#pragma unroll
    for (int i = 0; i < 4; ++i) av[i] = a4[i];
    float eas[DE] = { av[0].x, av[0].y, av[0].z, av[0].w,
                      av[1].x, av[1].y, av[1].z, av[1].w,
                      av[2].x, av[2].y, av[2].z, av[2].w,
                      av[3].x, av[3].y, av[3].z, av[3].w };

    // u[c] = bsum[c] + sum_d ea[d]*Wsum[d,c]   (wave-uniform LDS broadcasts)
    const float4* ws4 = (const float4*)ws;
    const float4* bs4 = (const float4*)(ws + 1024);
    float4 u[16];
#pragma unroll
    for (int c4 = 0; c4 < 16; ++c4) u[c4] = bs4[c4];
#pragma unroll
    for (int d = 0; d < DE; ++d) {
        float ed = eas[d];
#pragma unroll
        for (int c4 = 0; c4 < 16; ++c4) {
            float4 w = ws4[d * 16 + c4];
            u[c4].x += ed * w.x; u[c4].y += ed * w.y;
            u[c4].z += ed * w.z; u[c4].w += ed * w.w;
        }
    }

    // s_e = u . x[r]   (x = 2.56MB, L2-resident; 256B gather)
    const float4* x4 = (const float4*)(x + (size_t)r * CC);
    float acc = 0.f;
#pragma unroll
    for (int c4 = 0; c4 < 16; ++c4) {
        float4 xv = x4[c4];
        acc += u[c4].x * xv.x + u[c4].y * xv.y + u[c4].z * xv.z + u[c4].w * xv.w;
    }
    s[e] = acc;   // plain coalesced store -- no atomics
}

// ---- Kernel 2: slice-owned reduction + GEMM --------------------------------
__global__ __launch_bounds__(256) void k_reduce_gemm(const float* __restrict__ x,
                                                     const float* __restrict__ root,
                                                     const float* __restrict__ bias,
                                                     const int* __restrict__ ei,
                                                     const float* __restrict__ s,
                                                     float* __restrict__ out,
                                                     int N, int E, int SL) {
    __shared__ float rt[CC * CC];     // 16KB
    __shared__ float xs[16 * PAD];
    __shared__ float bi[CC];
    __shared__ float segs[SLMAX];
    __shared__ float cnts[SLMAX];
    __shared__ float mn[16];
    const int tid = threadIdx.x;
    const int n0 = blockIdx.x * SL;

    for (int i = tid; i < CC * CC; i += 256) rt[i] = root[i];
    if (tid < CC) bi[tid] = bias[tid];
    for (int i = tid; i < SL; i += 256) { segs[i] = 0.f; cnts[i] = 0.f; }
    __syncthreads();

    // scan all edges once: col[] coalesced (400KB, L3-resident); s[e] loaded
    // only on slice hit (~1.6% -> ~6KB/block), LDS atomic accumulate
    const int* __restrict__ col = ei + E;
#pragma unroll 4
    for (int e = tid; e < E; e += 256) {
        int c = col[e];
        unsigned l = (unsigned)(c - n0);
        if (l < (unsigned)SL) {
            atomicAdd(&segs[l], s[e]);
            atomicAdd(&cnts[l], 1.0f);
        }
    }
    __syncthreads();

    // GEMM over the slice in 16-node tiles (verified R5 k_final inner loop)
    const int nl = tid >> 4, ci = tid & 15;
    const float4* rt4 = (const float4*)rt;
    const float4* bi4 = (const float4*)bi;
    const int tiles = (SL + 15) >> 4;

    for (int t = 0; t < tiles; ++t) {
        int base = n0 + t * 16;
        __syncthreads();   // xs/mn free from previous tile
#pragma unroll
        for (int j = 0; j < 4; ++j) {
            int i = j * 256 + tid;            // 0..1023
            int rrow = t * 16 + (i >> 6);     // slice-local row
            if (rrow < SL && (size_t)base * CC + i < (size_t)N * CC)
                xs[(i >> 6) * PAD + (i & 63)] = x[(size_t)base * CC + i];
        }
        if (tid < 16) {
            int l = t * 16 + tid, n = base + tid;
            if (l < SL && n < N) {
                float c = cnts[l];
                mn[tid] = c > 0.5f ? segs[l] / (c * (float)CC) : 0.f;
            }
        }
        __syncthreads();
        int l = t * 16 + nl, n = base + nl;
        if (l < SL && n < N) {
            float m = mn[nl];
            float4 bv = bi4[ci];
            float4 acc = make_float4(bv.x + m, bv.y + m, bv.z + m, bv.w + m);
#pragma unroll
            for (int k = 0; k < CC; ++k) {
                float a  = xs[nl * PAD + k];   // bcast, padded banks
                float4 w = rt4[k * 16 + ci];   // 2-way alias = free
                acc.x += a * w.x; acc.y += a * w.y;
                acc.z += a * w.z; acc.w += a * w.w;
            }
            *(float4*)(out + (size_t)n * CC + ci * 4) = acc;
        }
    }
}

extern "C" void kernel_launch(void* const* d_in, const int* in_sizes, int n_in,
                              void* d_out, int out_size, void* d_ws, size_t ws_size,
                              hipStream_t stream) {
    const float* x    = (const float*)d_in[0];
    const int*   ei   = (const int*)  d_in[1];
    const float* ea   = (const float*)d_in[2];
    const float* W    = (const float*)d_in[3];
    const float* b    = (const float*)d_in[4];
    const float* root = (const float*)d_in[5];
    const float* bias = (const float*)d_in[6];
    float* out = (float*)d_out;
    float* ws  = (float*)d_ws;

    const int N = in_sizes[0] / CC;   // 10000
    const int E = in_sizes[1] / 2;    // 100000

    float* s = ws;                    // E floats, fully rewritten every call

    const int SL = (N + NB2 - 1) / NB2;   // 157 (<= SLMAX)
    int eBlocks = (E + 255) / 256;        // 391

    k_score      <<<eBlocks, 256, 0, stream>>>(W, b, x, ei, ea, s, E);
    k_reduce_gemm<<<NB2,     256, 0, stream>>>(x, root, bias, ei, s, out, N, E, SL);
}

// Round 10
// 135.234 us; speedup vs baseline: 1.8007x; 1.8007x over previous
//
#include <hip/hip_runtime.h>
#include <hip/hip_bf16.h>

// NNConv collapsed algebraically, 2 dispatches, NO global atomics, stateless:
//   K1 k_edge_hist: block b owns edges [b*782,(b+1)*782):
//       s_e = sum_c u_e[c]*x[row,c], u_e[c]=bsum[c]+sum_d ea[e,d]*Wsum[d,c]
//       LDS histogram (40KB): hist[col] += s_e + 65536   (packed seg+cnt,
//       one LDS atomic/edge), then coalesced plain-store flush ->
//       partial[b][N] (5.1MB ws, fully rewritten every call => replay-safe).
//   K2 k_final: per 16-node tile, owner threads sum 128 partials in DOUBLE,
//       decode cnt=rint(t/65536), seg=t-cnt*65536, mean=seg/(64*cnt);
//       then verified R5 tile GEMM: out = x@root + bias + mean.
//
// Session ladder (gfx950, measured):
//   grid.sync ~70us (R4) | manual spin ~70us (R6) | dispatch boundary ~2-3us
//   (R5) | global atomic scatter ~30-43us (R7) | whole-E scan per block,
//   latency-bound ~160us (R9) => only dense, coalesced, high-occupancy work.
// R8 proved workspace is NOT re-poisoned between replays: everything here is
// rewritten each call; LDS zeroed in-kernel; no cross-call invariants needed.
// Packing error budget: deg<=~27 (Poisson(10) tail), per-contributing-partial
// fp32 ulp ~0.03 at 3e5 => seg error <=~0.8 => out error <=~5e-4 << 0.119.

#define CC 64
#define DE 16
#define PAD 65       // xs row stride in k_final: 65%32=1 -> distinct banks
#define NPART 128    // histogram copies (= K1 grid)
#define HN 10240     // LDS histogram slots (>= N)
#define MARKF 65536.0f
#define MARKD 65536.0

// ---- Kernel 1: direct per-edge matvec + packed LDS histogram + flush -------
__global__ __launch_bounds__(256) void k_edge_hist(const float* __restrict__ W,
                                                   const float* __restrict__ b,
                                                   const float* __restrict__ x,
                                                   const int* __restrict__ ei,
                                                   const float* __restrict__ ea,
                                                   float* __restrict__ partial,
                                                   int N, int E) {
    __shared__ float ws[1024 + CC];   // Wsum(16x64) + bsum(64)
    __shared__ float hist[HN];        // packed seg+65536*cnt per node
    const int tid = threadIdx.x;

    // zero histogram
    for (int i = tid; i < HN; i += 256) hist[i] = 0.f;

    // Wsum/bsum: 1088 reductions of 64 contiguous floats (W=262KB, L2-resident)
    for (int p = tid; p < 1024 + CC; p += 256) {
        const float4* src = (p < 1024) ? (const float4*)(W + (size_t)p * CC)
                                       : (const float4*)(b + (size_t)(p - 1024) * CC);
        float v = 0.f;
#pragma unroll
        for (int i = 0; i < 16; ++i) { float4 q = src[i]; v += q.x + q.y + q.z + q.w; }
        ws[p] = v;
    }
    __syncthreads();

    const float4* ws4 = (const float4*)ws;
    const float4* bs4 = (const float4*)(ws + 1024);

    const int chunk = (E + NPART - 1) / NPART;          // 782
    const int e1 = min(E, (blockIdx.x + 1) * chunk);

    for (int e = blockIdx.x * chunk + tid; e < e1; e += 256) {
        const int r  = ei[e];
        const int cn = ei[E + e];

        const float4* a4 = (const float4*)(ea + (size_t)e * DE);
        float4 av[4];
#pragma unroll
        for (int i = 0; i < 4; ++i) av[i] = a4[i];
        float eas[DE] = { av[0].x, av[0].y, av[0].z, av[0].w,
                          av[1].x, av[1].y, av[1].z, av[1].w,
                          av[2].x, av[2].y, av[2].z, av[2].w,
                          av[3].x, av[3].y, av[3].z, av[3].w };

        // u[c] = bsum[c] + sum_d ea[d]*Wsum[d,c]  (wave-uniform LDS bcast)
        float4 u[16];
#pragma unroll
        for (int c4 = 0; c4 < 16; ++c4) u[c4] = bs4[c4];
#pragma unroll
        for (int d = 0; d < DE; ++d) {
            float ed = eas[d];
#pragma unroll
            for (int c4 = 0; c4 < 16; ++c4) {
                float4 w = ws4[d * 16 + c4];
                u[c4].x += ed * w.x; u[c4].y += ed * w.y;
                u[c4].z += ed * w.z; u[c4].w += ed * w.w;
            }
        }

        // s_e = u . x[r]  (x = 2.56MB, L2-resident; 256B gather)
        const float4* x4 = (const float4*)(x + (size_t)r * CC);
        float s = 0.f;
#pragma unroll
        for (int c4 = 0; c4 < 16; ++c4) {
            float4 xv = x4[c4];
            s += u[c4].x * xv.x + u[c4].y * xv.y + u[c4].z * xv.z + u[c4].w * xv.w;
        }

        atomicAdd(&hist[cn], s + MARKF);   // LDS atomic: cheap, intra-CU
    }
    __syncthreads();

    // flush: coalesced float4 plain stores (fully rewrites this copy)
    float4*       p4 = (float4*)(partial + (size_t)blockIdx.x * N);
    const float4* h4 = (const float4*)hist;
    for (int i = tid; i < N / 4; i += 256) p4[i] = h4[i];
}

// ---- Kernel 2: partial reduce (double) + verified tile GEMM ----------------
__global__ __launch_bounds__(256) void k_final(const float* __restrict__ x,
                                               const float* __restrict__ root,
                                               const float* __restrict__ bias,
                                               const float* __restrict__ partial,
                                               float* __restrict__ out,
                                               int N) {
    __shared__ float rt[CC * CC];      // 16 KB
    __shared__ float xs[16 * PAD];
    __shared__ float bi[CC];
    __shared__ float mn[16];
    int tid = threadIdx.x;
    int n0 = blockIdx.x * 16;

#pragma unroll
    for (int i = 0; i < 16; ++i) rt[tid + i * 256] = root[tid + i * 256];
#pragma unroll
    for (int it = 0; it < 4; ++it) {
        int i = it * 256 + tid;                 // 0..1023
        if ((size_t)n0 * CC + i < (size_t)N * CC)
            xs[(i >> 6) * PAD + (i & 63)] = x[(size_t)n0 * CC + i];
    }
    if (tid < CC) bi[tid] = bias[tid];
    if (tid < 16) {
        int n = n0 + tid;
        if (n < N) {
            double t = 0.0;
            for (int k = 0; k < NPART; ++k)
                t += (double)partial[(size_t)k * N + n];
            double c  = rint(t * (1.0 / MARKD));     // exact in-degree
            float  sg = (float)(t - c * MARKD);      // seg sum
            mn[tid] = c > 0.0 ? sg / ((float)c * (float)CC) : 0.f;
        } else mn[tid] = 0.f;
    }
    __syncthreads();

    int nl = tid >> 4, ci = tid & 15;
    int n = n0 + nl;
    if (n >= N) return;

    const float4* rt4 = (const float4*)rt;
    const float4* bi4 = (const float4*)bi;
    float m = mn[nl];
    float4 bv = bi4[ci];
    float4 acc = make_float4(bv.x + m, bv.y + m, bv.z + m, bv.w + m);
#pragma unroll
    for (int k = 0; k < CC; ++k) {
        float a  = xs[nl * PAD + k];        // bcast, padded banks
        float4 w = rt4[k * 16 + ci];        // 2-way alias = free
        acc.x += a * w.x; acc.y += a * w.y; acc.z += a * w.z; acc.w += a * w.w;
    }
    *(float4*)(out + (size_t)n * CC + ci * 4) = acc;
}

extern "C" void kernel_launch(void* const* d_in, const int* in_sizes, int n_in,
                              void* d_out, int out_size, void* d_ws, size_t ws_size,
                              hipStream_t stream) {
    const float* x    = (const float*)d_in[0];
    const int*   ei   = (const int*)  d_in[1];
    const float* ea   = (const float*)d_in[2];
    const float* W    = (const float*)d_in[3];
    const float* b    = (const float*)d_in[4];
    const float* root = (const float*)d_in[5];
    const float* bias = (const float*)d_in[6];
    float* out = (float*)d_out;
    float* ws  = (float*)d_ws;

    const int N = in_sizes[0] / CC;   // 10000
    const int E = in_sizes[1] / 2;    // 100000

    float* partial = ws;              // NPART*N floats = 5.12 MB, rewritten/call

    int fBlocks = (N + 15) / 16;      // 625

    k_edge_hist<<<NPART,  256, 0, stream>>>(W, b, x, ei, ea, partial, N, E);
    k_final    <<<fBlocks, 256, 0, stream>>>(x, root, bias, partial, out, N);
}